// Round 7
// baseline (248.021 us; speedup 1.0000x reference)
//
#include <hip/hip_runtime.h>
#include <math.h>

#define TWO_H 4096
#define HALF_H 2048
#define NGROUPS 8
#define BLOCK 256
#define WPB 4            // waves per block
#define RPW 4            // rows per wave
#define RPB (WPB * RPW)  // 16 consecutive rows per block (same expert group)

typedef int   vi4 __attribute__((ext_vector_type(4)));
typedef float vf4 __attribute__((ext_vector_type(4)));

// Block owns 16 consecutive rows (one group). W and B*W staged once into LDS
// in lane-major layout (16B/lane per ds_read_b128 -> conflict-free). Inner
// per-row loop: only streaming x loads + LDS reads + stores. One barrier per
// block; wave-private reduction via shfl.
__global__ __launch_bounds__(BLOCK, 4) void swiglu_requant_kernel(
    const int* __restrict__ x,         // [N, 4096] int32
    const float* __restrict__ wscale,  // [G, 4096]
    const float* __restrict__ ascale,  // [N]
    const float* __restrict__ bias,    // [4096]
    const float* __restrict__ qscale,  // [G]
    const int* __restrict__ gindex,    // [G]
    int* __restrict__ out,             // [N, 2048] int32 (int8 values widened)
    int n_rows)
{
    __shared__ float lds[4 * HALF_H];  // Wg | Wu | BWg | BWu (32 KiB)

    const int t     = threadIdx.x;
    const int lane  = t & 63;
    const int wslot = t >> 6;
    const int rblk  = blockIdx.x * RPB;
    if (rblk >= n_rows) return;

    int cum[NGROUPS];
    {
        int c = 0;
#pragma unroll
        for (int g = 0; g < NGROUPS; ++g) { c += gindex[g]; cum[g] = c; }
    }
#define GID_OF(row, dst) { int _g = 0; _Pragma("unroll") \
    for (int g = 0; g < NGROUPS; ++g) _g += ((row) >= cum[g]) ? 1 : 0; dst = _g; }

    int rlast = rblk + RPB - 1; if (rlast > n_rows - 1) rlast = n_rows - 1;
    int gid0, gidL;
    GID_OF(rblk, gid0);
    GID_OF(rlast, gidL);

    if (gid0 == gidL) {
        // ---- fast path: whole block in one group ----
        const float* wrow = wscale + (long)gid0 * TWO_H;

        // stage W and B*W, permuted: vf4 id v=(c*2+h)*64+l <-> col c*512+l*8+h*4
#pragma unroll
        for (int it = 0; it < 2; ++it) {
            const int v = t + it * BLOCK;        // [0,512)
            const int c = v >> 7, rem = v & 127;
            const int h = rem >> 6, l = rem & 63;
            const int colb = c * 512 + l * 8 + h * 4;
            vf4 wg = *(const vf4*)(wrow + colb);
            vf4 wu = *(const vf4*)(wrow + HALF_H + colb);
            vf4 bg = *(const vf4*)(bias + colb);
            vf4 bu = *(const vf4*)(bias + HALF_H + colb);
            *(vf4*)&lds[             v * 4] = wg;
            *(vf4*)&lds[    HALF_H + v * 4] = wu;
            *(vf4*)&lds[2 * HALF_H + v * 4] = wg * bg;
            *(vf4*)&lds[3 * HALF_H + v * 4] = wu * bu;
        }
        __syncthreads();

        const float q_s = qscale[gid0];
        const int rw0 = rblk + wslot * RPW;
        int rend = rw0 + RPW; if (rend > n_rows) rend = n_rows;

        for (int row = rw0; row < rend; ++row) {
            const float a_s = ascale[row];
            const int* xrow = x + (long)row * TWO_H;

            float o[32];
            float lmax = 0.0f;
#pragma unroll
            for (int c = 0; c < 4; ++c) {
                const int cg = c * 512 + lane * 8;
                vi4 g0 = *(const vi4*)(xrow + cg);
                vi4 g1 = *(const vi4*)(xrow + cg + 4);
                vi4 u0 = *(const vi4*)(xrow + HALF_H + cg);
                vi4 u1 = *(const vi4*)(xrow + HALF_H + cg + 4);

                const int v0 = ((c * 2 + 0) * 64 + lane) * 4;
                const int v1 = ((c * 2 + 1) * 64 + lane) * 4;
                vf4 Wg0 = *(const vf4*)&lds[v0],              Wg1 = *(const vf4*)&lds[v1];
                vf4 Wu0 = *(const vf4*)&lds[HALF_H + v0],     Wu1 = *(const vf4*)&lds[HALF_H + v1];
                vf4 Bg0 = *(const vf4*)&lds[2 * HALF_H + v0], Bg1 = *(const vf4*)&lds[2 * HALF_H + v1];
                vf4 Bu0 = *(const vf4*)&lds[3 * HALF_H + v0], Bu1 = *(const vf4*)&lds[3 * HALF_H + v1];

                float gi[8]  = {(float)g0.x, (float)g0.y, (float)g0.z, (float)g0.w,
                                (float)g1.x, (float)g1.y, (float)g1.z, (float)g1.w};
                float ui[8]  = {(float)u0.x, (float)u0.y, (float)u0.z, (float)u0.w,
                                (float)u1.x, (float)u1.y, (float)u1.z, (float)u1.w};
                float wg[8]  = {Wg0.x, Wg0.y, Wg0.z, Wg0.w, Wg1.x, Wg1.y, Wg1.z, Wg1.w};
                float wu[8]  = {Wu0.x, Wu0.y, Wu0.z, Wu0.w, Wu1.x, Wu1.y, Wu1.z, Wu1.w};
                float bwg[8] = {Bg0.x, Bg0.y, Bg0.z, Bg0.w, Bg1.x, Bg1.y, Bg1.z, Bg1.w};
                float bwu[8] = {Bu0.x, Bu0.y, Bu0.z, Bu0.w, Bu1.x, Bu1.y, Bu1.z, Bu1.w};

#pragma unroll
                for (int i = 0; i < 8; ++i) {
                    float gv = fmaf(gi[i], wg[i], bwg[i]) * a_s;
                    float uv = fmaf(ui[i], wu[i], bwu[i]) * a_s;
                    float e  = __expf(-uv);
                    float sv = uv * __builtin_amdgcn_rcpf(1.0f + e);  // silu(up)
                    float ov = sv * gv * q_s;
                    o[c * 8 + i] = ov;
                    lmax = fmaxf(lmax, fabsf(ov));
                }
            }

#pragma unroll
            for (int m = 1; m < 64; m <<= 1)
                lmax = fmaxf(lmax, __shfl_xor(lmax, m, 64));

            const float scale = 127.0f / lmax;
            int* orow = out + (long)row * HALF_H;
#pragma unroll
            for (int c = 0; c < 4; ++c) {
                const int co = c * 512 + lane * 8;
                int w[8];
#pragma unroll
                for (int i = 0; i < 8; ++i) {
                    float v = o[c * 8 + i] * scale;
                    v = fminf(fmaxf(v, -128.0f), 127.0f);
                    w[i] = (int)rintf(v);
                }
                vi4 w0 = {w[0], w[1], w[2], w[3]};
                vi4 w1 = {w[4], w[5], w[6], w[7]};
                *(vi4*)(orow + co)     = w0;
                *(vi4*)(orow + co + 4) = w1;
            }
        }
    } else {
        // ---- slow path (group boundary inside block; not hit with uniform groups) ----
        const int rw0 = rblk + wslot * RPW;
        int rend = rw0 + RPW; if (rend > n_rows) rend = n_rows;
        for (int row = rw0; row < rend; ++row) {
            int gid; GID_OF(row, gid);
            const float a_s = ascale[row];
            const float q_s = qscale[gid];
            const int*   xrow = x + (long)row * TWO_H;
            const float* wrow = wscale + (long)gid * TWO_H;

            float o[32];
            float lmax = 0.0f;
#pragma unroll
            for (int c = 0; c < 4; ++c) {
                const int cg = c * 512 + lane * 8;
#pragma unroll
                for (int i = 0; i < 8; ++i) {
                    float gv = ((float)xrow[cg + i] + bias[cg + i]) * wrow[cg + i] * a_s;
                    float uv = ((float)xrow[HALF_H + cg + i] + bias[HALF_H + cg + i]) *
                               wrow[HALF_H + cg + i] * a_s;
                    float e  = __expf(-uv);
                    float sv = uv * __builtin_amdgcn_rcpf(1.0f + e);
                    float ov = sv * gv * q_s;
                    o[c * 8 + i] = ov;
                    lmax = fmaxf(lmax, fabsf(ov));
                }
            }
#pragma unroll
            for (int m = 1; m < 64; m <<= 1)
                lmax = fmaxf(lmax, __shfl_xor(lmax, m, 64));
            const float scale = 127.0f / lmax;
            int* orow = out + (long)row * HALF_H;
#pragma unroll
            for (int c = 0; c < 4; ++c) {
                const int co = c * 512 + lane * 8;
#pragma unroll
                for (int i = 0; i < 8; ++i) {
                    float v = o[c * 8 + i] * scale;
                    v = fminf(fmaxf(v, -128.0f), 127.0f);
                    orow[co + i] = (int)rintf(v);
                }
            }
        }
    }
#undef GID_OF
}

extern "C" void kernel_launch(void* const* d_in, const int* in_sizes, int n_in,
                              void* d_out, int out_size, void* d_ws, size_t ws_size,
                              hipStream_t stream) {
    const int*   x      = (const int*)d_in[0];
    const float* wscale = (const float*)d_in[1];
    const float* ascale = (const float*)d_in[2];
    const float* bias   = (const float*)d_in[3];
    const float* qscale = (const float*)d_in[4];
    const int*   gindex = (const int*)d_in[5];
    int* out = (int*)d_out;

    const int n_rows = in_sizes[0] / TWO_H;  // 32768
    const int grid = (n_rows + RPB - 1) / RPB;  // 2048

    swiglu_requant_kernel<<<grid, BLOCK, 0, stream>>>(
        x, wscale, ascale, bias, qscale, gindex, out, n_rows);
}

// Round 8
// 208.978 us; speedup vs baseline: 1.1868x; 1.1868x over previous
//
#include <hip/hip_runtime.h>
#include <math.h>

#define TWO_H 4096
#define HALF_H 2048
#define NGROUPS 8
#define BLOCK 256
#define WPB 4            // waves per block
#define RPW 4            // consecutive rows per wave
#define RPB (WPB * RPW)  // 16 consecutive rows per block

typedef int   vi4 __attribute__((ext_vector_type(4)));
typedef float vf4 __attribute__((ext_vector_type(4)));

// One WAVE per row (64 lanes x 32 cols), registers only, no LDS, no barriers.
// Wave owns 4 CONSECUTIVE rows -> same expert group (typically): wscale row
// (16KB) + bias (16KB) stay L1-resident and are reused 4x; x-stream is a
// contiguous 64KB burst per wave.
__global__ __launch_bounds__(BLOCK, 4) void swiglu_requant_kernel(
    const int* __restrict__ x,         // [N, 4096] int32
    const float* __restrict__ wscale,  // [G, 4096]
    const float* __restrict__ ascale,  // [N]
    const float* __restrict__ bias,    // [4096]
    const float* __restrict__ qscale,  // [G]
    const int* __restrict__ gindex,    // [G]
    int* __restrict__ out,             // [N, 2048] int32 (int8 values widened)
    int n_rows)
{
    const int lane = threadIdx.x & 63;
    const int wid  = blockIdx.x * WPB + (threadIdx.x >> 6);

    const int r0 = wid * RPW;
    if (r0 >= n_rows) return;
    int rend = r0 + RPW; if (rend > n_rows) rend = n_rows;

    // group boundaries (cumsum), wave-uniform in registers
    int cum[NGROUPS];
    {
        int c = 0;
#pragma unroll
        for (int g = 0; g < NGROUPS; ++g) { c += gindex[g]; cum[g] = c; }
    }

    for (int row = r0; row < rend; ++row) {
        int gid = 0;
#pragma unroll
        for (int g = 0; g < NGROUPS; ++g) gid += (row >= cum[g]) ? 1 : 0;

        const float a_s = ascale[row];
        const float q_s = qscale[gid];

        const int*   xrow = x + (long)row * TWO_H;
        const float* wrow = wscale + (long)gid * TWO_H;

        float o[32];
        float lmax = 0.0f;

#pragma unroll
        for (int c = 0; c < 4; ++c) {
            const int cg = c * 512 + lane * 8;   // gate col start for this chunk

            vi4 g0 = *(const vi4*)(xrow + cg);
            vi4 g1 = *(const vi4*)(xrow + cg + 4);
            vi4 u0 = *(const vi4*)(xrow + HALF_H + cg);
            vi4 u1 = *(const vi4*)(xrow + HALF_H + cg + 4);

            vf4 wg0 = *(const vf4*)(wrow + cg);
            vf4 wg1 = *(const vf4*)(wrow + cg + 4);
            vf4 wu0 = *(const vf4*)(wrow + HALF_H + cg);
            vf4 wu1 = *(const vf4*)(wrow + HALF_H + cg + 4);

            vf4 bg0 = *(const vf4*)(bias + cg);
            vf4 bg1 = *(const vf4*)(bias + cg + 4);
            vf4 bu0 = *(const vf4*)(bias + HALF_H + cg);
            vf4 bu1 = *(const vf4*)(bias + HALF_H + cg + 4);

            float gi[8] = {(float)g0.x, (float)g0.y, (float)g0.z, (float)g0.w,
                           (float)g1.x, (float)g1.y, (float)g1.z, (float)g1.w};
            float ui[8] = {(float)u0.x, (float)u0.y, (float)u0.z, (float)u0.w,
                           (float)u1.x, (float)u1.y, (float)u1.z, (float)u1.w};
            float wgx[8] = {wg0.x, wg0.y, wg0.z, wg0.w, wg1.x, wg1.y, wg1.z, wg1.w};
            float wux[8] = {wu0.x, wu0.y, wu0.z, wu0.w, wu1.x, wu1.y, wu1.z, wu1.w};
            float bgx[8] = {bg0.x, bg0.y, bg0.z, bg0.w, bg1.x, bg1.y, bg1.z, bg1.w};
            float bux[8] = {bu0.x, bu0.y, bu0.z, bu0.w, bu1.x, bu1.y, bu1.z, bu1.w};

#pragma unroll
            for (int i = 0; i < 8; ++i) {
                float gv = (gi[i] + bgx[i]) * wgx[i] * a_s;
                float uv = (ui[i] + bux[i]) * wux[i] * a_s;
                float e  = __expf(-uv);
                float sv = uv * __builtin_amdgcn_rcpf(1.0f + e);  // silu(up)
                float ov = sv * gv * q_s;
                o[c * 8 + i] = ov;
                lmax = fmaxf(lmax, fabsf(ov));
            }
        }

        // 64-lane max reduce, registers only
#pragma unroll
        for (int m = 1; m < 64; m <<= 1)
            lmax = fmaxf(lmax, __shfl_xor(lmax, m, 64));

        const float scale = 127.0f / lmax;

        int* orow = out + (long)row * HALF_H;
#pragma unroll
        for (int c = 0; c < 4; ++c) {
            const int co = c * 512 + lane * 8;
            int w[8];
#pragma unroll
            for (int i = 0; i < 8; ++i) {
                float v = o[c * 8 + i] * scale;
                v = fminf(fmaxf(v, -128.0f), 127.0f);  // clip then round (matches ref)
                w[i] = (int)rintf(v);                   // round half-to-even
            }
            vi4 w0 = {w[0], w[1], w[2], w[3]};
            vi4 w1 = {w[4], w[5], w[6], w[7]};
            *(vi4*)(orow + co)     = w0;
            *(vi4*)(orow + co + 4) = w1;
        }
    }
}

extern "C" void kernel_launch(void* const* d_in, const int* in_sizes, int n_in,
                              void* d_out, int out_size, void* d_ws, size_t ws_size,
                              hipStream_t stream) {
    const int*   x      = (const int*)d_in[0];
    const float* wscale = (const float*)d_in[1];
    const float* ascale = (const float*)d_in[2];
    const float* bias   = (const float*)d_in[3];
    const float* qscale = (const float*)d_in[4];
    const int*   gindex = (const int*)d_in[5];
    int* out = (int*)d_out;

    const int n_rows = in_sizes[0] / TWO_H;  // 32768
    const int grid = (n_rows + RPB - 1) / RPB;  // 2048

    swiglu_requant_kernel<<<grid, BLOCK, 0, stream>>>(
        x, wscale, ascale, bias, qscale, gindex, out, n_rows);
}

// Round 10
// 167.350 us; speedup vs baseline: 1.4821x; 1.2487x over previous
//
#include <hip/hip_runtime.h>
#include <math.h>

#define TWO_H 4096
#define HALF_H 2048
#define NGROUPS 8
#define BLOCK 256
#define WPB 4      // waves per block
#define GRID 2048  // 8192 waves; grid-stride: 4 rows per wave at N=32768

typedef int    vi4 __attribute__((ext_vector_type(4)));
typedef float  vf4 __attribute__((ext_vector_type(4)));
typedef __fp16 vh2 __attribute__((ext_vector_type(2)));

// One WAVE per row (64 lanes), grid-stride interleaved mapping (R5's proven
// layout). No LDS, no barriers. Row buffer packed to f16 pairs (16 VGPR) and
// small chunks (4 elems) to fit 128 VGPR WITHOUT spills -> 4 waves/SIMD.
__global__ __launch_bounds__(BLOCK, 4) void swiglu_requant_kernel(
    const int* __restrict__ x,         // [N, 4096] int32
    const float* __restrict__ wscale,  // [G, 4096]
    const float* __restrict__ ascale,  // [N]
    const float* __restrict__ bias,    // [4096]
    const float* __restrict__ qscale,  // [G]
    const int* __restrict__ gindex,    // [G]
    int* __restrict__ out,             // [N, 2048] int32 (int8 values widened)
    int n_rows)
{
    const int lane   = threadIdx.x & 63;
    const int wid    = blockIdx.x * WPB + (threadIdx.x >> 6);
    const int nwaves = GRID * WPB;

    // group boundaries (cumsum), wave-uniform
    int cum[NGROUPS];
    {
        int c = 0;
#pragma unroll
        for (int g = 0; g < NGROUPS; ++g) { c += gindex[g]; cum[g] = c; }
    }

    for (int row = wid; row < n_rows; row += nwaves) {
        int gid = 0;
#pragma unroll
        for (int g = 0; g < NGROUPS; ++g) gid += (row >= cum[g]) ? 1 : 0;

        const float a_s = ascale[row];
        const float q_s = qscale[gid];

        const int*   xrow = x + (long)row * TWO_H;
        const float* wrow = wscale + (long)gid * TWO_H;

        vh2   o16[16];            // packed row buffer: 16 VGPR instead of 32
        float lmax = 0.0f;

#pragma unroll
        for (int c = 0; c < 8; ++c) {
            const int cg = c * 256 + lane * 4;   // gate col start (4 elems)

            vi4 g = *(const vi4*)(xrow + cg);
            vi4 u = *(const vi4*)(xrow + HALF_H + cg);
            vf4 wg = *(const vf4*)(wrow + cg);
            vf4 wu = *(const vf4*)(wrow + HALF_H + cg);
            vf4 bg = *(const vf4*)(bias + cg);
            vf4 bu = *(const vf4*)(bias + HALF_H + cg);

            float gi[4] = {(float)g.x, (float)g.y, (float)g.z, (float)g.w};
            float ui[4] = {(float)u.x, (float)u.y, (float)u.z, (float)u.w};
            float wgx[4] = {wg.x, wg.y, wg.z, wg.w};
            float wux[4] = {wu.x, wu.y, wu.z, wu.w};
            float bgx[4] = {bg.x, bg.y, bg.z, bg.w};
            float bux[4] = {bu.x, bu.y, bu.z, bu.w};

            float ov[4];
#pragma unroll
            for (int i = 0; i < 4; ++i) {
                float gv = (gi[i] + bgx[i]) * wgx[i] * a_s;
                float uv = (ui[i] + bux[i]) * wux[i] * a_s;
                float e  = __expf(-uv);
                float sv = uv * __builtin_amdgcn_rcpf(1.0f + e);  // silu(up)
                float o  = sv * gv * q_s;
                ov[i] = o;
                lmax = fmaxf(lmax, fabsf(o));
            }
            // pack to f16 pairs (v_cvt_pkrtz_f16_f32) — frees registers
            o16[c * 2]     = __builtin_amdgcn_cvt_pkrtz(ov[0], ov[1]);
            o16[c * 2 + 1] = __builtin_amdgcn_cvt_pkrtz(ov[2], ov[3]);
        }

        // 64-lane max reduce, registers only (lmax is exact f32)
#pragma unroll
        for (int m = 1; m < 64; m <<= 1)
            lmax = fmaxf(lmax, __shfl_xor(lmax, m, 64));

        const float scale = 127.0f / lmax;

        int* orow = out + (long)row * HALF_H;
#pragma unroll
        for (int c = 0; c < 8; ++c) {
            const int co = c * 256 + lane * 4;
            float ov[4] = {(float)o16[c * 2].x,     (float)o16[c * 2].y,
                           (float)o16[c * 2 + 1].x, (float)o16[c * 2 + 1].y};
            int w[4];
#pragma unroll
            for (int i = 0; i < 4; ++i) {
                float v = ov[i] * scale;
                v = fminf(fmaxf(v, -128.0f), 127.0f);  // clip then round (matches ref)
                w[i] = (int)rintf(v);                   // round half-to-even
            }
            vi4 wv = {w[0], w[1], w[2], w[3]};
            *(vi4*)(orow + co) = wv;
        }
    }
}

extern "C" void kernel_launch(void* const* d_in, const int* in_sizes, int n_in,
                              void* d_out, int out_size, void* d_ws, size_t ws_size,
                              hipStream_t stream) {
    const int*   x      = (const int*)d_in[0];
    const float* wscale = (const float*)d_in[1];
    const float* ascale = (const float*)d_in[2];
    const float* bias   = (const float*)d_in[3];
    const float* qscale = (const float*)d_in[4];
    const int*   gindex = (const int*)d_in[5];
    int* out = (int*)d_out;

    const int n_rows = in_sizes[0] / TWO_H;  // 32768

    swiglu_requant_kernel<<<GRID, BLOCK, 0, stream>>>(
        x, wscale, ascale, bias, qscale, gindex, out, n_rows);
}